// Round 10
// baseline (119.439 us; speedup 1.0000x reference)
//
#include <hip/hip_runtime.h>

// B=1e6 rows, N=64 heads, D=3.
// u[b,n,k] = tanh(x[b,:]·W[n,k,:] + bias[n,k]); out_k[b] = sum_n u[b,n,k]*c_k[n].
// d_out: [0..B)=rho, [B..2B)=p, [2B..3B)=u  (f32).
//
// tanh(h) = 1 - 2/(1+exp2(K*h)), K=2*log2(e) folded into W,b (setup kernel).
// C-fold: out_k = C_k - 2*sum_n c_k[n]*inv_k[n], C_k = sum_n c_k[n].
// One rcp per row serves all 3 channels (cofactor trick).
// Constants live in a d_ws table read at loop-uniform addresses -> s_load into
// SGPRs (SMEM pipe). Zero LDS, no barriers.
//
// R9 change (single lever): RPT 2->1 for 2x resident waves (grid 3907 ~ 15/CU
// queued), scalar 16-float records (s_load_dwordx16 per head), unroll 4 ->
// 12 independent exp2 chains per thread. Busy floor ~34 us is trans-dominated;
// this round closes the 17 us stall gap via TLP.

#define NN   64
#define BLK  256

__device__ __forceinline__ float fexp2(float x) {
#if __has_builtin(__builtin_amdgcn_exp2f)
    return __builtin_amdgcn_exp2f(x);
#else
    return exp2f(x);
#endif
}
__device__ __forceinline__ float frcp(float x) {
#if __has_builtin(__builtin_amdgcn_rcpf)
    return __builtin_amdgcn_rcpf(x);
#else
    return 1.0f / x;
#endif
}

// ws layout (floats): [n*16 .. n*16+16) = record for head n:
//   {K*W[9], K*b[3], crho, cp, cu, pad}
// [1024..1027) = C0, C1, C2 (sum of c over n).
__global__ __launch_bounds__(64) void setup_tab(
    const float* __restrict__ W, const float* __restrict__ bias,
    const float* __restrict__ c_rho, const float* __restrict__ c_p,
    const float* __restrict__ c_u, float* __restrict__ ws)
{
    const int t = threadIdx.x;            // 64 threads == 64 heads == 1 wave
    const float K = 2.8853900817779268f;  // 2*log2(e)
    float* rec = ws + t * 16;
    #pragma unroll
    for (int j = 0; j < 9; ++j) rec[j] = W[t * 9 + j] * K;
    #pragma unroll
    for (int k = 0; k < 3; ++k) rec[9 + k] = bias[t * 3 + k] * K;
    const float cr = c_rho[t], cp = c_p[t], cu = c_u[t];
    rec[12] = cr; rec[13] = cp; rec[14] = cu; rec[15] = 0.0f;

    float C0 = cr, C1 = cp, C2 = cu;
    #pragma unroll
    for (int o = 1; o < 64; o <<= 1) {
        C0 += __shfl_xor(C0, o);
        C1 += __shfl_xor(C1, o);
        C2 += __shfl_xor(C2, o);
    }
    if (t == 0) { ws[1024] = C0; ws[1025] = C1; ws[1026] = C2; }
}

__global__ __launch_bounds__(BLK) void fused_tanh_heads(
    const float* __restrict__ x,    // [B,3]
    const float* __restrict__ ws,   // table from setup_tab
    float* __restrict__ out,        // [3*B]
    int B)
{
    const float C0 = ws[1024], C1 = ws[1025], C2 = ws[1026];

    const int r = blockIdx.x * BLK + threadIdx.x;
    const bool ok = (r < B);
    const float x0 = ok ? x[r * 3 + 0] : 0.0f;
    const float x1 = ok ? x[r * 3 + 1] : 0.0f;
    const float x2 = ok ? x[r * 3 + 2] : 0.0f;

    float acc0 = 0.0f, acc1 = 0.0f, acc2 = 0.0f;

    const float4* __restrict__ q4 = (const float4*)ws;  // 4 float4 per record
    #pragma unroll 4
    for (int n = 0; n < NN; ++n) {
        const float4 q0 = q4[n * 4 + 0];  // W0 W1 W2 W3   (xK)
        const float4 q1 = q4[n * 4 + 1];  // W4 W5 W6 W7   (xK)
        const float4 q2 = q4[n * 4 + 2];  // W8 b0 b1 b2   (xK)
        const float4 q3 = q4[n * 4 + 3];  // crho cp cu pad

        const float h0 = fmaf(x2, q0.z, fmaf(x1, q0.y, fmaf(x0, q0.x, q2.y)));
        const float h1 = fmaf(x2, q1.y, fmaf(x1, q1.x, fmaf(x0, q0.w, q2.z)));
        const float h2 = fmaf(x2, q2.x, fmaf(x1, q1.w, fmaf(x0, q1.z, q2.w)));

        const float a0 = fexp2(h0) + 1.0f;   // (1, ~2^16): no overflow
        const float a1 = fexp2(h1) + 1.0f;
        const float a2 = fexp2(h2) + 1.0f;

        // one rcp for all 3 channels: inv_i = cof_i * rcp(prod)
        const float m  = a0 * a1;
        const float R  = frcp(m * a2);       // product <= ~1.4e14, safe
        const float i2 = m  * R;
        const float s  = a2 * R;
        const float i0 = a1 * s;
        const float i1 = a0 * s;

        acc0 = fmaf(i0, q3.x, acc0);
        acc1 = fmaf(i1, q3.y, acc1);
        acc2 = fmaf(i2, q3.z, acc2);
    }

    if (ok) {
        out[r]         = fmaf(-2.0f, acc0, C0);
        out[B + r]     = fmaf(-2.0f, acc1, C1);
        out[2 * B + r] = fmaf(-2.0f, acc2, C2);
    }
}

extern "C" void kernel_launch(void* const* d_in, const int* in_sizes, int n_in,
                              void* d_out, int out_size, void* d_ws, size_t ws_size,
                              hipStream_t stream) {
    (void)ws_size; (void)n_in; (void)out_size;
    const float* x     = (const float*)d_in[0];
    const float* W     = (const float*)d_in[1];
    const float* bias  = (const float*)d_in[2];
    const float* c_rho = (const float*)d_in[3];
    const float* c_p   = (const float*)d_in[4];
    const float* c_u   = (const float*)d_in[5];
    float* out = (float*)d_out;
    float* ws  = (float*)d_ws;   // needs 1027*4 bytes

    const int B = in_sizes[0] / 3;
    const int grid = (B + BLK - 1) / BLK;

    setup_tab<<<1, 64, 0, stream>>>(W, bias, c_rho, c_p, c_u, ws);
    fused_tanh_heads<<<grid, BLK, 0, stream>>>(x, ws, out, B);
}